// Round 4
// baseline (139.036 us; speedup 1.0000x reference)
//
#include <hip/hip_runtime.h>
#include <hip/hip_bf16.h>

typedef __attribute__((ext_vector_type(8))) short short8;
typedef __attribute__((ext_vector_type(8))) unsigned short ushort8;
typedef __attribute__((ext_vector_type(4))) unsigned short u16x4;
typedef __attribute__((ext_vector_type(4))) float floatx4;

#define B_SZ 4
#define N_SZ 1024
#define DIM_SZ 1024
#define H_SZ 16
#define HD_SZ 64
#define M_TOT 4096          // B*N
#define NOUT 2048           // stacked Q|K output dim
#define HS_ELEMS 4194304    // 4096*1024
#define W_ELEMS  1048576    // 1024*1024
#define CVT_TOT  6291456    // HS + 2*W
#define WB_OFF   HS_ELEMS   // ws elem offset of stacked bf16 weights [2048][1024]
#define CB_OFF   CVT_TOT    // ws elem offset of C = [4096][2048] bf16 (Q cols 0-1023, K 1024-2047)

__device__ __forceinline__ unsigned short f2bf(float x) {
  union { float f; unsigned u; } v; v.f = x;
  unsigned r = v.u + 0x7FFFu + ((v.u >> 16) & 1u);  // round-to-nearest-even
  return (unsigned short)(r >> 16);
}

typedef const __attribute__((address_space(1))) void GASV;
typedef __attribute__((address_space(3))) void LASV;
#define GLL16(g, l) __builtin_amdgcn_global_load_lds((GASV*)(g), (LASV*)(l), 16, 0, 0)

// ---------------- Phase 0: f32 -> bf16 pre-convert (hs, Wq|Wk stacked) -----
__global__ __launch_bounds__(256) void convert_bf16(
    const float* __restrict__ hs, const float* __restrict__ Wq,
    const float* __restrict__ Wk, unsigned short* __restrict__ ws)
{
  size_t i = ((size_t)blockIdx.x * 256 + threadIdx.x) * 8;
  const float* src;
  if (i < HS_ELEMS) src = hs + i;
  else if (i < HS_ELEMS + W_ELEMS) src = Wq + (i - HS_ELEMS);
  else src = Wk + (i - HS_ELEMS - W_ELEMS);
  floatx4 v0 = *reinterpret_cast<const floatx4*>(src);
  floatx4 v1 = *reinterpret_cast<const floatx4*>(src + 4);
  ushort8 o;
#pragma unroll
  for (int j = 0; j < 4; ++j) { o[j] = f2bf(v0[j]); o[4 + j] = f2bf(v1[j]); }
  *reinterpret_cast<ushort8*>(ws + i) = o;
}

// ---------------- Phase 1: fused Q|K projection GEMM (m97 structure) -------
// C[m][o] = sum_k hsb[m][k] * Wb[o][k]; 128x128 tile, BK=32, global_load_lds.
// Operands SWAPPED (A=W, B=hs) so each lane owns 4 consecutive o-cols ->
// u16x4 packed stores.
__global__ __launch_bounds__(256) void proj_gemm(
    const unsigned short* __restrict__ ws_ro, unsigned short* __restrict__ Cb)
{
  const unsigned short* hsb = ws_ro;
  const unsigned short* Wb = ws_ro + WB_OFF;
  __shared__ unsigned short As[128 * 32];
  __shared__ unsigned short Bs[128 * 32];
  const int tid = threadIdx.x, lane = tid & 63, wave = tid >> 6;
  const int fr = lane & 15, k8 = (lane >> 4) * 8;
  const int wr = wave >> 1, wc = wave & 1;
  const int mbase = blockIdx.x * 128, obase = blockIdx.y * 128;

  const unsigned short* ag = hsb + (size_t)(mbase + (tid >> 2)) * DIM_SZ + (tid & 3) * 8;
  const unsigned short* bg = Wb + (size_t)(obase + (tid >> 2)) * DIM_SZ + (tid & 3) * 8;
  unsigned short* lA = &As[tid * 8];
  unsigned short* lB = &Bs[tid * 8];

  floatx4 acc[4][4];
#pragma unroll
  for (int o4 = 0; o4 < 4; ++o4)
#pragma unroll
    for (int m4 = 0; m4 < 4; ++m4) acc[o4][m4] = floatx4{0.f, 0.f, 0.f, 0.f};

  for (int k0 = 0; k0 < DIM_SZ; k0 += 32) {
    GLL16(ag + k0, lA);
    GLL16(ag + k0 + 64 * DIM_SZ, lA + 2048);
    GLL16(bg + k0, lB);
    GLL16(bg + k0 + 64 * DIM_SZ, lB + 2048);
    __syncthreads();
    short8 wf[4], hf[4];
#pragma unroll
    for (int o4 = 0; o4 < 4; ++o4)
      wf[o4] = *reinterpret_cast<const short8*>(&Bs[(wc * 64 + o4 * 16 + fr) * 32 + k8]);
#pragma unroll
    for (int m4 = 0; m4 < 4; ++m4)
      hf[m4] = *reinterpret_cast<const short8*>(&As[(wr * 64 + m4 * 16 + fr) * 32 + k8]);
#pragma unroll
    for (int o4 = 0; o4 < 4; ++o4)
#pragma unroll
      for (int m4 = 0; m4 < 4; ++m4)
        acc[o4][m4] = __builtin_amdgcn_mfma_f32_16x16x32_bf16(wf[o4], hf[m4], acc[o4][m4], 0, 0, 0);
    __syncthreads();
  }

  // D layout: col(lane&15) = m row, row((lane>>4)*4+r) = o col -> 4 consecutive o
  const int g4 = (lane >> 4) * 4;
#pragma unroll
  for (int o4 = 0; o4 < 4; ++o4)
#pragma unroll
    for (int m4 = 0; m4 < 4; ++m4) {
      int mrow = mbase + wr * 64 + m4 * 16 + fr;
      int ocol = obase + wc * 64 + o4 * 16 + g4;
      u16x4 pk;
#pragma unroll
      for (int r = 0; r < 4; ++r) pk[r] = f2bf(acc[o4][m4][r]);
      *reinterpret_cast<u16x4*>(&Cb[(size_t)mrow * NOUT + ocol]) = pk;
    }
}

// ---------------- Phase 2: scores + softmax + shaped-attention epilogue ----
// Swapped operands: mfma(K_frag, Q_frag) -> lane holds S[qbase+fr][kb+g*4+r]
// -> float4 stores, scalar row-sum with 2 shuffles.
__global__ __launch_bounds__(256) void attn_out(
    const unsigned short* __restrict__ Cb,   // [4096][2048] bf16: Q | K
    const int* __restrict__ mask,
    const float* __restrict__ g1p,
    const float* __restrict__ g2p,
    const float* __restrict__ g3p,
    float* __restrict__ out)
{
  const int bh = blockIdx.y;       // b*16 + h
  const int b = bh >> 4;
  const int h = bh & 15;
  const int qbase = blockIdx.x * 16;
  const int tid = threadIdx.x;
  const int lane = tid & 63;
  const int wave = tid >> 6;

  __shared__ float nzf[N_SZ];
  __shared__ float wsum[4];
  __shared__ float rowsums[4][16];

  float cnt = 0.f;
  for (int i = tid; i < N_SZ; i += 256) {
    float v = (mask[b * N_SZ + i] == 0) ? 1.0f : 0.0f;
    nzf[i] = v;
    cnt += v;
  }
#pragma unroll
  for (int off = 32; off >= 1; off >>= 1) cnt += __shfl_xor(cnt, off);
  if (lane == 0) wsum[wave] = cnt;
  __syncthreads();
  const float nnz = wsum[0] + wsum[1] + wsum[2] + wsum[3];

  const int fr = lane & 15;
  const int k8 = (lane >> 4) * 8;

  // Q fragment (B operand): N index = q = qbase+fr, k-chunk = (lane>>4)*8
  const unsigned short* qptr =
      Cb + (size_t)(b * N_SZ + qbase + fr) * NOUT + h * HD_SZ + k8;
  short8 qa0 = *reinterpret_cast<const short8*>(qptr);
  short8 qa1 = *reinterpret_cast<const short8*>(qptr + 32);

  floatx4 acc[16];
#pragma unroll
  for (int c = 0; c < 16; ++c) acc[c] = floatx4{0.f, 0.f, 0.f, 0.f};

#pragma unroll
  for (int c = 0; c < 16; ++c) {
    int krow = wave * 256 + c * 16 + fr;  // A-operand M index = key index
    const unsigned short* kp =
        Cb + (size_t)(b * N_SZ + krow) * NOUT + N_SZ + h * HD_SZ + k8;
    short8 kb0 = *reinterpret_cast<const short8*>(kp);
    short8 kb1 = *reinterpret_cast<const short8*>(kp + 32);
    acc[c] = __builtin_amdgcn_mfma_f32_16x16x32_bf16(kb0, qa0, acc[c], 0, 0, 0);
    acc[c] = __builtin_amdgcn_mfma_f32_16x16x32_bf16(kb1, qa1, acc[c], 0, 0, 0);
  }

  // softmax (logits ~0.04 in magnitude: max-subtraction unnecessary)
  const float expscale = 0.015625f * 1.44269504f;  // SCALE * log2(e)
  float psum = 0.f;
#pragma unroll
  for (int c = 0; c < 16; ++c) {
#pragma unroll
    for (int r = 0; r < 4; ++r) {
      float p = __builtin_amdgcn_exp2f(acc[c][r] * expscale);
      acc[c][r] = p;
      psum += p;
    }
  }
  psum += __shfl_xor(psum, 16);
  psum += __shfl_xor(psum, 32);
  if (lane < 16) rowsums[wave][lane] = psum;
  __syncthreads();

  const float g1 = *g1p, g2 = *g2p, g3 = *g3p;
  const float g3n = g3 / nnz;
  const float rs = rowsums[0][fr] + rowsums[1][fr] + rowsums[2][fr] + rowsums[3][fr];
  const float inv = g2 / rs;
  const int q = qbase + fr;
  const float nzq = nzf[q];
  const float g3nq = g3n * nzq;
  const float g1q = g1 * nzq;
  float* orow = out + (size_t)(bh * N_SZ + q) * N_SZ;
  const int g4 = (lane >> 4) * 4;

#pragma unroll
  for (int c = 0; c < 16; ++c) {
    int kb = wave * 256 + c * 16 + g4;   // 4 consecutive key cols
    floatx4 nzk = *reinterpret_cast<const floatx4*>(&nzf[kb]);
    floatx4 v;
#pragma unroll
    for (int r = 0; r < 4; ++r) v[r] = acc[c][r] * inv - g3nq * nzk[r];
    unsigned dq = (unsigned)(q - kb);
    if (dq < 4u) v[dq] += g1q;           // diagonal term
    *reinterpret_cast<floatx4*>(&orow[kb]) = v;
  }
}

extern "C" void kernel_launch(void* const* d_in, const int* in_sizes, int n_in,
                              void* d_out, int out_size, void* d_ws, size_t ws_size,
                              hipStream_t stream) {
  const float* hs = (const float*)d_in[0];
  const int* mask = (const int*)d_in[1];
  const float* Wq = (const float*)d_in[2];
  const float* Wk = (const float*)d_in[3];
  const float* g1 = (const float*)d_in[4];
  const float* g2 = (const float*)d_in[5];
  const float* g3 = (const float*)d_in[6];
  float* out = (float*)d_out;
  unsigned short* ws = (unsigned short*)d_ws;

  convert_bf16<<<CVT_TOT / (256 * 8), 256, 0, stream>>>(hs, Wq, Wk, ws);
  proj_gemm<<<dim3(M_TOT / 128, NOUT / 128), 256, 0, stream>>>(ws, ws + CB_OFF);
  attn_out<<<dim3(N_SZ / 16, B_SZ * H_SZ), 256, 0, stream>>>(
      ws + CB_OFF, mask, g1, g2, g3, out);
}

// Round 5
// 138.922 us; speedup vs baseline: 1.0008x; 1.0008x over previous
//
#include <hip/hip_runtime.h>
#include <hip/hip_bf16.h>

typedef __attribute__((ext_vector_type(8))) short short8;
typedef __attribute__((ext_vector_type(8))) unsigned short ushort8;
typedef __attribute__((ext_vector_type(4))) unsigned short u16x4;
typedef __attribute__((ext_vector_type(4))) float floatx4;

#define B_SZ 4
#define N_SZ 1024
#define DIM_SZ 1024
#define H_SZ 16
#define HD_SZ 64
#define M_TOT 4096          // B*N
#define NOUT 2048           // stacked Q|K output dim
#define HS_ELEMS 4194304    // 4096*1024
#define W_ELEMS  1048576    // 1024*1024
#define CVT_TOT  6291456    // HS + 2*W
#define WB_OFF   HS_ELEMS   // ws elem offset of stacked bf16 weights [2048][1024]
#define CB_OFF   CVT_TOT    // ws elem offset of C = [4096][2048] bf16 (Q cols 0-1023, K 1024-2047)

__device__ __forceinline__ unsigned short f2bf(float x) {
  union { float f; unsigned u; } v; v.f = x;
  unsigned r = v.u + 0x7FFFu + ((v.u >> 16) & 1u);  // round-to-nearest-even
  return (unsigned short)(r >> 16);
}

typedef const __attribute__((address_space(1))) void GASV;
typedef __attribute__((address_space(3))) void LASV;
#define GLL16(g, l) __builtin_amdgcn_global_load_lds((GASV*)(g), (LASV*)(l), 16, 0, 0)

// ---------------- Phase 0: f32 -> bf16 pre-convert (hs, Wq|Wk stacked) -----
__global__ __launch_bounds__(256) void convert_bf16(
    const float* __restrict__ hs, const float* __restrict__ Wq,
    const float* __restrict__ Wk, unsigned short* __restrict__ ws)
{
  size_t i = ((size_t)blockIdx.x * 256 + threadIdx.x) * 8;
  const float* src;
  if (i < HS_ELEMS) src = hs + i;
  else if (i < HS_ELEMS + W_ELEMS) src = Wq + (i - HS_ELEMS);
  else src = Wk + (i - HS_ELEMS - W_ELEMS);
  floatx4 v0 = *reinterpret_cast<const floatx4*>(src);
  floatx4 v1 = *reinterpret_cast<const floatx4*>(src + 4);
  ushort8 o;
#pragma unroll
  for (int j = 0; j < 4; ++j) { o[j] = f2bf(v0[j]); o[4 + j] = f2bf(v1[j]); }
  *reinterpret_cast<ushort8*>(ws + i) = o;
}

// ---------------- Phase 1: fused Q|K projection GEMM (m97 structure) -------
// C[m][o] = sum_k hsb[m][k] * Wb[o][k]; 128x128 tile, BK=32, global_load_lds.
// Operands SWAPPED (A=W, B=hs) so each lane owns 4 consecutive o-cols ->
// u16x4 packed stores. XCD-clustered block swizzle (512 blocks, 512%8==0).
__global__ __launch_bounds__(256) void proj_gemm(
    const unsigned short* __restrict__ ws_ro, unsigned short* __restrict__ Cb)
{
  const unsigned short* hsb = ws_ro;
  const unsigned short* Wb = ws_ro + WB_OFF;
  __shared__ unsigned short As[128 * 32];
  __shared__ unsigned short Bs[128 * 32];
  const int tid = threadIdx.x, lane = tid & 63, wave = tid >> 6;
  const int fr = lane & 15, k8 = (lane >> 4) * 8;
  const int wr = wave >> 1, wc = wave & 1;

  // XCD swizzle: cluster 64 consecutive logical blocks (4 mbase panels) per XCD
  const int hw = blockIdx.x + gridDim.x * blockIdx.y;   // 512 blocks
  const int swz = (hw & 7) * 64 + (hw >> 3);
  const int mbase = (swz >> 4) * 128;    // 32 m-tiles
  const int obase = (swz & 15) * 128;    // 16 o-tiles

  const unsigned short* ag = hsb + (size_t)(mbase + (tid >> 2)) * DIM_SZ + (tid & 3) * 8;
  const unsigned short* bg = Wb + (size_t)(obase + (tid >> 2)) * DIM_SZ + (tid & 3) * 8;
  unsigned short* lA = &As[tid * 8];
  unsigned short* lB = &Bs[tid * 8];

  floatx4 acc[4][4];
#pragma unroll
  for (int o4 = 0; o4 < 4; ++o4)
#pragma unroll
    for (int m4 = 0; m4 < 4; ++m4) acc[o4][m4] = floatx4{0.f, 0.f, 0.f, 0.f};

  for (int k0 = 0; k0 < DIM_SZ; k0 += 32) {
    GLL16(ag + k0, lA);
    GLL16(ag + k0 + 64 * DIM_SZ, lA + 2048);
    GLL16(bg + k0, lB);
    GLL16(bg + k0 + 64 * DIM_SZ, lB + 2048);
    __syncthreads();
    short8 wf[4], hf[4];
#pragma unroll
    for (int o4 = 0; o4 < 4; ++o4)
      wf[o4] = *reinterpret_cast<const short8*>(&Bs[(wc * 64 + o4 * 16 + fr) * 32 + k8]);
#pragma unroll
    for (int m4 = 0; m4 < 4; ++m4)
      hf[m4] = *reinterpret_cast<const short8*>(&As[(wr * 64 + m4 * 16 + fr) * 32 + k8]);
#pragma unroll
    for (int o4 = 0; o4 < 4; ++o4)
#pragma unroll
      for (int m4 = 0; m4 < 4; ++m4)
        acc[o4][m4] = __builtin_amdgcn_mfma_f32_16x16x32_bf16(wf[o4], hf[m4], acc[o4][m4], 0, 0, 0);
    __syncthreads();
  }

  // D layout: col(lane&15) = m row, row((lane>>4)*4+r) = o col -> 4 consecutive o
  const int g4 = (lane >> 4) * 4;
#pragma unroll
  for (int o4 = 0; o4 < 4; ++o4)
#pragma unroll
    for (int m4 = 0; m4 < 4; ++m4) {
      int mrow = mbase + wr * 64 + m4 * 16 + fr;
      int ocol = obase + wc * 64 + o4 * 16 + g4;
      u16x4 pk;
#pragma unroll
      for (int r = 0; r < 4; ++r) pk[r] = f2bf(acc[o4][m4][r]);
      *reinterpret_cast<u16x4*>(&Cb[(size_t)mrow * NOUT + ocol]) = pk;
    }
}

// ---------------- Phase 2: scores + softmax + shaped-attention epilogue ----
// mfma(K_frag, Q_frag) -> lane holds S[qbase+fr][kb+g*4+r] -> float4 stores.
// XCD-clustered swizzle: 8 consecutive bh per XCD (K panel L2-resident).
__global__ __launch_bounds__(256) void attn_out(
    const unsigned short* __restrict__ Cb,   // [4096][2048] bf16: Q | K
    const int* __restrict__ mask,
    const float* __restrict__ g1p,
    const float* __restrict__ g2p,
    const float* __restrict__ g3p,
    float* __restrict__ out)
{
  // 4096 blocks: logical id = qtile (64) fastest, bh (64) slowest
  const int hw = blockIdx.x + gridDim.x * blockIdx.y;
  const int swz = (hw & 7) * 512 + (hw >> 3);
  const int bh = swz >> 6;
  const int qbase = (swz & 63) * 16;
  const int b = bh >> 4;
  const int h = bh & 15;
  const int tid = threadIdx.x;
  const int lane = tid & 63;
  const int wave = tid >> 6;

  __shared__ float nzf[N_SZ];
  __shared__ float wsum[4];
  __shared__ float rowsums[4][16];

  float cnt = 0.f;
  for (int i = tid; i < N_SZ; i += 256) {
    float v = (mask[b * N_SZ + i] == 0) ? 1.0f : 0.0f;
    nzf[i] = v;
    cnt += v;
  }
#pragma unroll
  for (int off = 32; off >= 1; off >>= 1) cnt += __shfl_xor(cnt, off);
  if (lane == 0) wsum[wave] = cnt;
  __syncthreads();
  const float nnz = wsum[0] + wsum[1] + wsum[2] + wsum[3];

  const int fr = lane & 15;
  const int k8 = (lane >> 4) * 8;

  // Q fragment (B operand): N index = q = qbase+fr, k-chunk = (lane>>4)*8
  const unsigned short* qptr =
      Cb + (size_t)(b * N_SZ + qbase + fr) * NOUT + h * HD_SZ + k8;
  short8 qa0 = *reinterpret_cast<const short8*>(qptr);
  short8 qa1 = *reinterpret_cast<const short8*>(qptr + 32);

  floatx4 acc[16];
#pragma unroll
  for (int c = 0; c < 16; ++c) acc[c] = floatx4{0.f, 0.f, 0.f, 0.f};

#pragma unroll
  for (int c = 0; c < 16; ++c) {
    int krow = wave * 256 + c * 16 + fr;  // A-operand M index = key index
    const unsigned short* kp =
        Cb + (size_t)(b * N_SZ + krow) * NOUT + N_SZ + h * HD_SZ + k8;
    short8 kb0 = *reinterpret_cast<const short8*>(kp);
    short8 kb1 = *reinterpret_cast<const short8*>(kp + 32);
    acc[c] = __builtin_amdgcn_mfma_f32_16x16x32_bf16(kb0, qa0, acc[c], 0, 0, 0);
    acc[c] = __builtin_amdgcn_mfma_f32_16x16x32_bf16(kb1, qa1, acc[c], 0, 0, 0);
  }

  // softmax (logits ~0.04 in magnitude: max-subtraction unnecessary)
  const float expscale = 0.015625f * 1.44269504f;  // SCALE * log2(e)
  float psum = 0.f;
#pragma unroll
  for (int c = 0; c < 16; ++c) {
#pragma unroll
    for (int r = 0; r < 4; ++r) {
      float p = __builtin_amdgcn_exp2f(acc[c][r] * expscale);
      acc[c][r] = p;
      psum += p;
    }
  }
  psum += __shfl_xor(psum, 16);
  psum += __shfl_xor(psum, 32);
  if (lane < 16) rowsums[wave][lane] = psum;
  __syncthreads();

  const float g1 = *g1p, g2 = *g2p, g3 = *g3p;
  const float g3n = g3 / nnz;
  const float rs = rowsums[0][fr] + rowsums[1][fr] + rowsums[2][fr] + rowsums[3][fr];
  const float inv = g2 / rs;
  const int q = qbase + fr;
  const float nzq = nzf[q];
  const float g3nq = g3n * nzq;
  const float g1q = g1 * nzq;
  float* orow = out + (size_t)(bh * N_SZ + q) * N_SZ;
  const int g4 = (lane >> 4) * 4;

#pragma unroll
  for (int c = 0; c < 16; ++c) {
    int kb = wave * 256 + c * 16 + g4;   // 4 consecutive key cols
    floatx4 nzk = *reinterpret_cast<const floatx4*>(&nzf[kb]);
    floatx4 v;
#pragma unroll
    for (int r = 0; r < 4; ++r) {
      v[r] = acc[c][r] * inv - g3nq * nzk[r];
      v[r] += (q == kb + r) ? g1q : 0.f;   // diagonal; STATIC index (rule #20)
    }
    *reinterpret_cast<floatx4*>(&orow[kb]) = v;
  }
}

extern "C" void kernel_launch(void* const* d_in, const int* in_sizes, int n_in,
                              void* d_out, int out_size, void* d_ws, size_t ws_size,
                              hipStream_t stream) {
  const float* hs = (const float*)d_in[0];
  const int* mask = (const int*)d_in[1];
  const float* Wq = (const float*)d_in[2];
  const float* Wk = (const float*)d_in[3];
  const float* g1 = (const float*)d_in[4];
  const float* g2 = (const float*)d_in[5];
  const float* g3 = (const float*)d_in[6];
  float* out = (float*)d_out;
  unsigned short* ws = (unsigned short*)d_ws;

  convert_bf16<<<CVT_TOT / (256 * 8), 256, 0, stream>>>(hs, Wq, Wk, ws);
  proj_gemm<<<dim3(M_TOT / 128, NOUT / 128), 256, 0, stream>>>(ws, ws + CB_OFF);
  attn_out<<<dim3(N_SZ / 16, B_SZ * H_SZ), 256, 0, stream>>>(
      ws + CB_OFF, mask, g1, g2, g3, out);
}